// Round 7
// baseline (2791.546 us; speedup 1.0000x reference)
//
#include <hip/hip_runtime.h>
#include <math.h>

#define BB 512
#define SS 16
#define HH 501
#define CC 7
#define OFF_ENC (BB*SS*SS)

// workspace float offsets (weights only)
#define O_WLIN  0
#define O_WPOST 262144
#define O_WHH   (O_WPOST + 524288)
#define O_WDOT  (O_WHH + 786432)

typedef __attribute__((ext_vector_type(8))) short bfrag;   // 8 bf16 = 4 VGPR
typedef __attribute__((ext_vector_type(4))) float ffrag;   // 4 f32 acc

__device__ __forceinline__ float sigm(float x) { return 1.f / (1.f + expf(-x)); }

__device__ __forceinline__ unsigned short f2bf(float x) {
    unsigned u = __float_as_uint(x);
    u = u + 0x7fffu + ((u >> 16) & 1u);          // RNE
    return (unsigned short)(u >> 16);
}
__device__ __forceinline__ float bf2f(unsigned short h) {
    return __uint_as_float(((unsigned)h) << 16);
}

// ---------- weight repack kernel (proven r1-r6 layout) ----------------------
__global__ __launch_bounds__(256) void k_wprep(
    const float* __restrict__ Wlin1, const float* __restrict__ Wgate,
    const float* __restrict__ Wmap,  const float* __restrict__ Whh,
    const float* __restrict__ Wedge, const float* __restrict__ Wvert,
    unsigned short* __restrict__ wlin, unsigned short* __restrict__ wpost,
    unsigned short* __restrict__ whhf, unsigned short* __restrict__ wdot)
{
    const int id = blockIdx.x * 256 + threadIdx.x;
    const int slot = id >> 10, rem = id & 1023, s = rem >> 6, lane = rem & 63;
    const int rloc = lane & 15;
    const int k0 = s * 32 + ((lane >> 4) << 3);
    const float* src; unsigned short* dst; int dslot; bool valid;
    if (slot < 32) {
        int row = slot * 16 + rloc; valid = row < HH;
        src = Wlin1 + (size_t)(valid ? row : 0) * HH; dst = wlin; dslot = slot;
    } else if (slot < 96) {
        int p = slot - 32, g = p >> 5, mt = p & 31;
        int row = mt * 16 + rloc; valid = row < HH;
        src = (g ? Wmap : Wgate) + (size_t)(valid ? row : 0) * HH; dst = wpost; dslot = p;
    } else if (slot < 192) {
        int p = slot - 96, g = p >> 5, mt = p & 31;
        int row = mt * 16 + rloc; valid = row < HH;
        src = Whh + (size_t)(g * HH + (valid ? row : 0)) * HH; dst = whhf; dslot = p;
    } else {
        int row = rloc; dst = wdot; dslot = 0;
        if (row < 2)      { src = Wedge + (size_t)row * HH; valid = true; }
        else if (row < 9) { src = Wvert + (size_t)(row - 2) * HH; valid = true; }
        else              { src = Wedge; valid = false; }
    }
    unsigned h[8], l[8];
#pragma unroll
    for (int j = 0; j < 8; ++j) {
        int k = k0 + j;
        float w = (valid && k < HH) ? src[k] : 0.f;
        unsigned short hb = f2bf(w);
        h[j] = hb; l[j] = f2bf(w - bf2f(hb));
    }
    size_t base = ((size_t)dslot * 32 + s * 2) * 512 + lane * 8;
    uint4 uh, ul;
    uh.x = h[0] | (h[1] << 16); uh.y = h[2] | (h[3] << 16);
    uh.z = h[4] | (h[5] << 16); uh.w = h[6] | (h[7] << 16);
    ul.x = l[0] | (l[1] << 16); ul.y = l[2] | (l[3] << 16);
    ul.z = l[4] | (l[5] << 16); ul.w = l[6] | (l[7] << 16);
    *(uint4*)&dst[base] = uh;
    *(uint4*)&dst[base + 512] = ul;
}

// ---------- LDS helpers (swizzled [col][512] bf16 planes) -------------------
// 16B-granule g of column c lives at position (g ^ (c&7))
__device__ __forceinline__ void writeT(unsigned short* p0, unsigned short* p1,
                                       int c, int mt, int l4, const float* v) {
    unsigned h[4], l[4];
#pragma unroll
    for (int i = 0; i < 4; ++i) {
        unsigned short hb = f2bf(v[i]);
        h[i] = hb; l[i] = f2bf(v[i] - bf2f(hb));
    }
    uint2 uh, ul;
    uh.x = h[0] | (h[1] << 16); uh.y = h[2] | (h[3] << 16);
    ul.x = l[0] | (l[1] << 16); ul.y = l[2] | (l[3] << 16);
    const int g = mt * 2 + (l4 >> 1);
    const int off = ((g ^ (c & 7)) << 3) + ((l4 & 1) << 2);
    *(uint2*)(p0 + (size_t)c * 512 + off) = uh;
    *(uint2*)(p1 + (size_t)c * 512 + off) = ul;
}

__device__ __forceinline__ void readH(const unsigned short* p0, const unsigned short* p1,
                                      int c, int mt, int l4, float* hp) {
    const int g = mt * 2 + (l4 >> 1);
    const int off = (g ^ (c & 7)) << 3;
    uint4 vh = *(const uint4*)(p0 + (size_t)c * 512 + off);
    uint4 vl = *(const uint4*)(p1 + (size_t)c * 512 + off);
    uint2 uh, ul;
    if (l4 & 1) { uh.x = vh.z; uh.y = vh.w; ul.x = vl.z; ul.y = vl.w; }
    else        { uh.x = vh.x; uh.y = vh.y; ul.x = vl.x; ul.y = vl.y; }
    hp[0] = bf2f(uh.x & 0xffff) + bf2f(ul.x & 0xffff);
    hp[1] = bf2f(uh.x >> 16)    + bf2f(ul.x >> 16);
    hp[2] = bf2f(uh.y & 0xffff) + bf2f(ul.y & 0xffff);
    hp[3] = bf2f(uh.y >> 16)    + bf2f(ul.y >> 16);
}

// ---------- MFMA core: A from global (L2-warm), B from LDS ------------------
template<int G>
__device__ __forceinline__ void gcore(
    const unsigned short* __restrict__ wf,
    const unsigned short* p0, const unsigned short* p1,
    int mt, int c, int l4, int lane, ffrag* acc)
{
    const char* wp = (const char*)wf + (size_t)lane * 16;
#pragma unroll
    for (int s = 0; s < 16; ++s) {
        const int off = (((s * 4 + l4) ^ (c & 7)) << 3);
        bfrag bh = *(const bfrag*)(p0 + (size_t)c * 512 + off);
        bfrag bl = *(const bfrag*)(p1 + (size_t)c * 512 + off);
#pragma unroll
        for (int g = 0; g < G; ++g) {
            const char* ap = wp + (size_t)((g * 32 + mt) * 32 + s * 2) * 1024;
            bfrag ah = *(const bfrag*)ap;
            bfrag al = *(const bfrag*)(ap + 1024);
            acc[g] = __builtin_amdgcn_mfma_f32_16x16x32_bf16(ah, bh, acc[g], 0, 0, 0);
            acc[g] = __builtin_amdgcn_mfma_f32_16x16x32_bf16(ah, bl, acc[g], 0, 0, 0);
            acc[g] = __builtin_amdgcn_mfma_f32_16x16x32_bf16(al, bh, acc[g], 0, 0, 0);
        }
    }
}

// ---------- the per-column-group fused kernel (no grid sync) ----------------
__global__ __launch_bounds__(1024, 1) void k_fused(
    const float* __restrict__ z, const float* __restrict__ dep,
    const float* __restrict__ xenc,
    const float* __restrict__ blin1,
    const float* __restrict__ bvert, const float* __restrict__ bedge,
    const float* __restrict__ bgate, const float* __restrict__ bmap,
    const float* __restrict__ Wih, const float* __restrict__ bih,
    const float* __restrict__ bhh,
    const unsigned short* __restrict__ wlin,
    const unsigned short* __restrict__ wpost,
    const unsigned short* __restrict__ whhf,
    const unsigned short* __restrict__ wdot,
    float* __restrict__ out)
{
    __shared__ unsigned short SA[2][2][16][512];   // [buf][plane][col][k] 64 KB
    __shared__ float sdls[16][17];
    __shared__ float sAl[16][16];
    __shared__ float sEl[16][16];
    __shared__ int   scls[16][16];

    const int tid = threadIdx.x, lane = tid & 63, wv = tid >> 6;
    const int l4 = lane >> 4, c = lane & 15;
    const int c0 = blockIdx.x * 16;
    const int bgl = c0 + c;                       // global batch col of this lane

    unsigned short* H0 = &SA[0][0][0][0];  unsigned short* H1 = &SA[0][1][0][0];  // buf0 = z / h
    unsigned short* I0 = &SA[1][0][0][0];  unsigned short* I1 = &SA[1][1][0][0];  // buf1 = h_in

    // ---- stage 0: z -> buf0 (transposed, split), cls, zero dep-out slice ----
    {
        const int lc = tid >> 6, kc = tid & 63;   // col 0..15, 8-elem granule 0..63
        const float* zp = z + (size_t)(c0 + lc) * HH + kc * 8;
        unsigned h[8], l[8];
#pragma unroll
        for (int j = 0; j < 8; ++j) {
            int k = kc * 8 + j;
            float w = (k < HH) ? zp[j] : 0.f;
            unsigned short hb = f2bf(w);
            h[j] = hb; l[j] = f2bf(w - bf2f(hb));
        }
        uint4 uh, ul;
        uh.x = h[0] | (h[1] << 16); uh.y = h[2] | (h[3] << 16);
        uh.z = h[4] | (h[5] << 16); uh.w = h[6] | (h[7] << 16);
        ul.x = l[0] | (l[1] << 16); ul.y = l[2] | (l[3] << 16);
        ul.z = l[4] | (l[5] << 16); ul.w = l[6] | (l[7] << 16);
        const int off = ((kc ^ (lc & 7)) << 3);
        *(uint4*)(H0 + (size_t)lc * 512 + off) = uh;
        *(uint4*)(H1 + (size_t)lc * 512 + off) = ul;
    }
    if (tid < 256) {
        const int ts = tid >> 4, lc = tid & 15;
        const float* xp = xenc + ((size_t)(c0 + lc) * SS + ts) * CC;
        int cv = 0;
#pragma unroll
        for (int cc = 0; cc < CC; ++cc) if (xp[cc] > 0.5f) cv = cc;
        scls[ts][lc] = cv;
    }
    {
        const int lc = tid >> 6, q = tid & 63;    // zero this block's dep-out slice
        ((float4*)(out + (size_t)(c0 + lc) * (SS * SS)))[q] =
            make_float4(0.f, 0.f, 0.f, 0.f);
    }
    __syncthreads();

    // ---- g0 = z @ Wlin1^T + b  (buf0 -> buf1) ----
#pragma unroll
    for (int u = 0; u < 2; ++u) {
        const int mt = wv * 2 + u;
        ffrag acc = {0.f, 0.f, 0.f, 0.f};
        gcore<1>(wlin, H0, H1, mt, c, l4, lane, &acc);
        const int rbase = mt * 16 + (l4 << 2);
        float v[4];
#pragma unroll
        for (int r = 0; r < 4; ++r) {
            int rr = rbase + r;
            v[r] = (rr < HH) ? acc[r] + blin1[rr] : 0.f;
        }
        writeT(I0, I1, c, mt, l4, v);
    }
    __syncthreads();

    // ---- 16 timesteps, all in-block ----
    for (int idx = 0; idx < SS; ++idx) {
        // stage A: gru (buf1 -> buf0); wave0 also dots-phase1 on buf1 at idx==0
#pragma unroll
        for (int u = 0; u < 2; ++u) {
            const int mt = wv * 2 + u;
            ffrag acc[3];
#pragma unroll
            for (int i = 0; i < 3; ++i) acc[i] = ffrag{0.f, 0.f, 0.f, 0.f};
            gcore<3>(whhf, I0, I1, mt, c, l4, lane, acc);
            float hp[4];
            readH(I0, I1, c, mt, l4, hp);
            const int rbase = mt * 16 + (l4 << 2);
            const int cc = scls[idx][c];
            float v[4];
#pragma unroll
            for (int r = 0; r < 4; ++r) {
                int rr = rbase + r;
                if (rr < HH) {
                    float ar  = acc[0][r];
                    float az  = acc[1][r];
                    float an2 = acc[2][r];
                    float rgt = sigm(Wih[(size_t)rr * CC + cc] + bih[rr] + ar + bhh[rr]);
                    float ugt = sigm(Wih[(size_t)(HH + rr) * CC + cc] + bih[HH + rr] + az + bhh[HH + rr]);
                    float ngt = tanhf(Wih[(size_t)(2 * HH + rr) * CC + cc] + bih[2 * HH + rr]
                                      + rgt * (an2 + bhh[2 * HH + rr]));
                    v[r] = (1.f - ugt) * ngt + ugt * hp[r];
                } else v[r] = 0.f;
            }
            writeT(H0, H1, c, mt, l4, v);
        }
        if (wv == 0 && idx == 0) {
            // dots(-1) on h_in(0) = buf1
            ffrag acc = {0.f, 0.f, 0.f, 0.f};
            const char* wp = (const char*)wdot + (size_t)lane * 16;
#pragma unroll
            for (int s = 0; s < 16; ++s) {
                const int off = (((s * 4 + l4) ^ (c & 7)) << 3);
                bfrag bh = *(const bfrag*)(I0 + (size_t)c * 512 + off);
                bfrag bl = *(const bfrag*)(I1 + (size_t)c * 512 + off);
                bfrag ah = *(const bfrag*)(wp + (size_t)(s * 2) * 1024);
                bfrag al = *(const bfrag*)(wp + (size_t)(s * 2) * 1024 + 1024);
                acc = __builtin_amdgcn_mfma_f32_16x16x32_bf16(ah, bh, acc, 0, 0, 0);
                acc = __builtin_amdgcn_mfma_f32_16x16x32_bf16(ah, bl, acc, 0, 0, 0);
                acc = __builtin_amdgcn_mfma_f32_16x16x32_bf16(al, bh, acc, 0, 0, 0);
            }
#pragma unroll
            for (int r = 0; r < 4; ++r) sdls[(l4 << 2) + r][c] = acc[r];
        }
        __syncthreads();
        if (idx == 0 && tid < 16) {
            // dots(-1) phase2: enc row 0 only
            float v[9];
#pragma unroll
            for (int j = 0; j < 9; ++j) v[j] = sdls[j][tid];
            float lv[CC], mx = -1e30f;
#pragma unroll
            for (int q = 0; q < CC; ++q) { lv[q] = v[2 + q] + bvert[q]; mx = fmaxf(mx, lv[q]); }
            float sum = 0.f, ev[CC];
#pragma unroll
            for (int q = 0; q < CC; ++q) { ev[q] = expf(lv[q] - mx); sum += ev[q]; }
            float inv = 1.f / sum;
#pragma unroll
            for (int q = 0; q < CC; ++q)
                out[OFF_ENC + ((size_t)(c0 + tid) * SS + 0) * CC + q] = ev[q] * inv;
        }
        // stage B: post (buf0 -> buf1); wave0 also dots-phase1 on buf0
        if (idx < SS - 1) {
#pragma unroll
            for (int u = 0; u < 2; ++u) {
                const int mt = wv * 2 + u;
                ffrag acc[2];
                acc[0] = ffrag{0.f, 0.f, 0.f, 0.f}; acc[1] = ffrag{0.f, 0.f, 0.f, 0.f};
                gcore<2>(wpost, H0, H1, mt, c, l4, lane, acc);
                const int rbase = mt * 16 + (l4 << 2);
                const float d = dep[(size_t)bgl * (SS * SS) + (idx + 1) * SS + idx];
                float v[4];
#pragma unroll
                for (int r = 0; r < 4; ++r) {
                    int rr = rbase + r;
                    if (rr < HH) {
                        float bg = bgate[rr], bm = bmap[rr];
                        float cv = sigm(bg) * bm;
                        float f = sigm(acc[0][r] + bg) * (acc[1][r] + bm);
                        v[r] = (d != 0.f) ? (f + 15.f * cv) : (16.f * cv);
                    } else v[r] = 0.f;
                }
                writeT(I0, I1, c, mt, l4, v);
            }
        }
        if (wv == 0) {
            // dots(idx) on h = buf0
            ffrag acc = {0.f, 0.f, 0.f, 0.f};
            const char* wp = (const char*)wdot + (size_t)lane * 16;
#pragma unroll
            for (int s = 0; s < 16; ++s) {
                const int off = (((s * 4 + l4) ^ (c & 7)) << 3);
                bfrag bh = *(const bfrag*)(H0 + (size_t)c * 512 + off);
                bfrag bl = *(const bfrag*)(H1 + (size_t)c * 512 + off);
                bfrag ah = *(const bfrag*)(wp + (size_t)(s * 2) * 1024);
                bfrag al = *(const bfrag*)(wp + (size_t)(s * 2) * 1024 + 1024);
                acc = __builtin_amdgcn_mfma_f32_16x16x32_bf16(ah, bh, acc, 0, 0, 0);
                acc = __builtin_amdgcn_mfma_f32_16x16x32_bf16(ah, bl, acc, 0, 0, 0);
                acc = __builtin_amdgcn_mfma_f32_16x16x32_bf16(al, bh, acc, 0, 0, 0);
            }
#pragma unroll
            for (int r = 0; r < 4; ++r) sdls[(l4 << 2) + r][c] = acc[r];
        }
        __syncthreads();
        if (tid < 16) {
            // dots(idx) phase2
            const int b = c0 + tid;
            float v[9];
#pragma unroll
            for (int j = 0; j < 9; ++j) v[j] = sdls[j][tid];
            sAl[idx][tid] = v[0]; sEl[idx][tid] = v[1];
            if (idx <= SS - 2) {
                float lv[CC], mx = -1e30f;
#pragma unroll
                for (int q = 0; q < CC; ++q) { lv[q] = v[2 + q] + bvert[q]; mx = fmaxf(mx, lv[q]); }
                float sum = 0.f, ev[CC];
#pragma unroll
                for (int q = 0; q < CC; ++q) { ev[q] = expf(lv[q] - mx); sum += ev[q]; }
                float inv = 1.f / sum;
#pragma unroll
                for (int q = 0; q < CC; ++q)
                    out[OFF_ENC + ((size_t)b * SS + (idx + 1)) * CC + q] = ev[q] * inv;
            }
            if (idx >= 1) {
                float be = bedge[0];
                float aprev = sAl[idx - 1][tid], eprev = sEl[idx - 1][tid];
                out[(size_t)b * SS * SS + idx * SS + (idx - 1)] =
                    (aprev + eprev + be >= 0.f) ? 1.f : 0.f;
                for (int vj = 0; vj <= idx - 2; ++vj)
                    out[(size_t)b * SS * SS + idx * SS + vj] =
                        (v[0] + sEl[vj][tid] + be >= 0.f) ? 1.f : 0.f;
            }
        }
    }
}

extern "C" void kernel_launch(void* const* d_in, const int* in_sizes, int n_in,
                              void* d_out, int out_size, void* d_ws, size_t ws_size,
                              hipStream_t stream)
{
    const float* z     = (const float*)d_in[0];
    const float* dep   = (const float*)d_in[1];
    const float* xenc  = (const float*)d_in[2];
    const float* Wlin1 = (const float*)d_in[3];
    const float* blin1 = (const float*)d_in[4];
    const float* Wvert = (const float*)d_in[5];
    const float* bvert = (const float*)d_in[6];
    const float* Wedge = (const float*)d_in[7];
    const float* bedge = (const float*)d_in[8];
    const float* Wgate = (const float*)d_in[9];
    const float* bgate = (const float*)d_in[10];
    const float* Wmap  = (const float*)d_in[11];
    const float* bmap  = (const float*)d_in[12];
    const float* Wih   = (const float*)d_in[13];
    const float* bih   = (const float*)d_in[14];
    const float* Whh   = (const float*)d_in[15];
    const float* bhh   = (const float*)d_in[16];
    float* out = (float*)d_out;
    float* ws  = (float*)d_ws;

    unsigned short* wlin  = (unsigned short*)(ws + O_WLIN);
    unsigned short* wpost = (unsigned short*)(ws + O_WPOST);
    unsigned short* whhf  = (unsigned short*)(ws + O_WHH);
    unsigned short* wdot  = (unsigned short*)(ws + O_WDOT);

    k_wprep<<<772, 256, 0, stream>>>(Wlin1, Wgate, Wmap, Whh, Wedge, Wvert,
                                     wlin, wpost, whhf, wdot);
    k_fused<<<32, 1024, 0, stream>>>(z, dep, xenc, blin1, bvert, bedge,
                                     bgate, bmap, Wih, bih, bhh,
                                     wlin, wpost, whhf, wdot, out);
}

// Round 9
// 1443.926 us; speedup vs baseline: 1.9333x; 1.9333x over previous
//
#include <hip/hip_runtime.h>
#include <math.h>

#define BB 512
#define SS 16
#define HH 501
#define CC 7
#define OFF_ENC (BB*SS*SS)

// workspace float offsets
#define O_WLIN  0
#define O_WPOST 262144
#define O_WHH   786432
#define O_WDOT  1572864
#define O_FLAGS 1581056          // 2048 ints (FH 1024 | FI 1024)
#define O_ROT   1589248          // 1024 slots x 16384 ushorts = 32 MB

#define NBLK 64
#define NTHR 1024

typedef __attribute__((ext_vector_type(8))) short bfrag;   // 8 bf16 = 4 VGPR
typedef __attribute__((ext_vector_type(4))) float ffrag;   // 4 f32 acc

__device__ __forceinline__ float sigm(float x) { return 1.f / (1.f + expf(-x)); }

__device__ __forceinline__ unsigned short f2bf(float x) {
    unsigned u = __float_as_uint(x);
    u = u + 0x7fffu + ((u >> 16) & 1u);          // RNE
    return (unsigned short)(u >> 16);
}
__device__ __forceinline__ float bf2f(unsigned short h) {
    return __uint_as_float(((unsigned)h) << 16);
}

// ---------- weight repack (identical to proven r1-r7 layout) ----------------
__global__ __launch_bounds__(256) void k_wprep(
    const float* __restrict__ Wlin1, const float* __restrict__ Wgate,
    const float* __restrict__ Wmap,  const float* __restrict__ Whh,
    const float* __restrict__ Wedge, const float* __restrict__ Wvert,
    unsigned short* __restrict__ wlin, unsigned short* __restrict__ wpost,
    unsigned short* __restrict__ whhf, unsigned short* __restrict__ wdot)
{
    const int id = blockIdx.x * 256 + threadIdx.x;
    const int slot = id >> 10, rem = id & 1023, s = rem >> 6, lane = rem & 63;
    const int rloc = lane & 15;
    const int k0 = s * 32 + ((lane >> 4) << 3);
    const float* src; unsigned short* dst; int dslot; bool valid;
    if (slot < 32) {
        int row = slot * 16 + rloc; valid = row < HH;
        src = Wlin1 + (size_t)(valid ? row : 0) * HH; dst = wlin; dslot = slot;
    } else if (slot < 96) {
        int p = slot - 32, g = p >> 5, mt = p & 31;
        int row = mt * 16 + rloc; valid = row < HH;
        src = (g ? Wmap : Wgate) + (size_t)(valid ? row : 0) * HH; dst = wpost; dslot = p;
    } else if (slot < 192) {
        int p = slot - 96, g = p >> 5, mt = p & 31;
        int row = mt * 16 + rloc; valid = row < HH;
        src = Whh + (size_t)(g * HH + (valid ? row : 0)) * HH; dst = whhf; dslot = p;
    } else {
        int row = rloc; dst = wdot; dslot = 0;
        if (row < 2)      { src = Wedge + (size_t)row * HH; valid = true; }
        else if (row < 9) { src = Wvert + (size_t)(row - 2) * HH; valid = true; }
        else              { src = Wedge; valid = false; }
    }
    unsigned h[8], l[8];
#pragma unroll
    for (int j = 0; j < 8; ++j) {
        int k = k0 + j;
        float w = (valid && k < HH) ? src[k] : 0.f;
        unsigned short hb = f2bf(w);
        h[j] = hb; l[j] = f2bf(w - bf2f(hb));
    }
    size_t base = ((size_t)dslot * 32 + s * 2) * 512 + lane * 8;
    uint4 uh, ul;
    uh.x = h[0] | (h[1] << 16); uh.y = h[2] | (h[3] << 16);
    uh.z = h[4] | (h[5] << 16); uh.w = h[6] | (h[7] << 16);
    ul.x = l[0] | (l[1] << 16); ul.y = l[2] | (l[3] << 16);
    ul.z = l[4] | (l[5] << 16); ul.w = l[6] | (l[7] << 16);
    *(uint4*)&dst[base] = uh;
    *(uint4*)&dst[base + 512] = ul;
}

__global__ void k_finit(int* bars) {
    int i = blockIdx.x * 256 + threadIdx.x;
    if (i < 2048) bars[i] = 0;
}

// ---------- flag ops (r5/r6-proven pattern) ---------------------------------
__device__ __forceinline__ void setflag(int* f) {
    __hip_atomic_store(f, 1, __ATOMIC_RELEASE, __HIP_MEMORY_SCOPE_AGENT);
}
__device__ __forceinline__ void waitpair(int* f) {
    if (threadIdx.x == 0) {
        while (!__hip_atomic_load(f + 0, __ATOMIC_RELAXED, __HIP_MEMORY_SCOPE_AGENT))
            __builtin_amdgcn_s_sleep(2);
        while (!__hip_atomic_load(f + 1, __ATOMIC_RELAXED, __HIP_MEMORY_SCOPE_AGENT))
            __builtin_amdgcn_s_sleep(2);
    }
    __syncthreads();
}

// ---------- slot <-> LDS helpers --------------------------------------------
// slot layout: plane0 [16 col][512] ushorts, plane1 at +8192
// LDS layout:  same but 16B-granule g stored at (g ^ (col&7))
__device__ __forceinline__ void stage_slot_lds(
    const unsigned short* __restrict__ slot, unsigned short* __restrict__ BL, int tid)
{
    const uint4* g4 = (const uint4*)slot;
#pragma unroll
    for (int q = 0; q < 2; ++q) {
        int i = q * 1024 + tid;
        uint4 v = g4[i];
        int pl = i >> 10, rem = i & 1023, col = rem >> 6, gr = rem & 63;
        *(uint4*)(BL + pl * 8192 + col * 512 + ((gr ^ (col & 7)) << 3)) = v;
    }
}

__device__ __forceinline__ void store_slot(unsigned short* __restrict__ slot,
                                           int c, int rbase, const float* v) {
    unsigned h[4], l[4];
#pragma unroll
    for (int i = 0; i < 4; ++i) {
        unsigned short hb = f2bf(v[i]);
        h[i] = hb; l[i] = f2bf(v[i] - bf2f(hb));
    }
    uint2 uh, ul;
    uh.x = h[0] | (h[1] << 16); uh.y = h[2] | (h[3] << 16);
    ul.x = l[0] | (l[1] << 16); ul.y = l[2] | (l[3] << 16);
    *(uint2*)&slot[c * 512 + rbase] = uh;
    *(uint2*)&slot[8192 + c * 512 + rbase] = ul;
}

__device__ __forceinline__ void readH(const unsigned short* p0, const unsigned short* p1,
                                      int c, int mt, int l4, float* hp) {
    const int g = mt * 2 + (l4 >> 1);
    const int off = (g ^ (c & 7)) << 3;
    uint4 vh = *(const uint4*)(p0 + (size_t)c * 512 + off);
    uint4 vl = *(const uint4*)(p1 + (size_t)c * 512 + off);
    uint2 uh, ul;
    if (l4 & 1) { uh.x = vh.z; uh.y = vh.w; ul.x = vl.z; ul.y = vl.w; }
    else        { uh.x = vh.x; uh.y = vh.y; ul.x = vl.x; ul.y = vl.y; }
    hp[0] = bf2f(uh.x & 0xffff) + bf2f(ul.x & 0xffff);
    hp[1] = bf2f(uh.x >> 16)    + bf2f(ul.x >> 16);
    hp[2] = bf2f(uh.y & 0xffff) + bf2f(ul.y & 0xffff);
    hp[3] = bf2f(uh.y >> 16)    + bf2f(ul.y >> 16);
}

// ---------- MFMA core with A from GLOBAL (used once, for g0) ----------------
template<int G>
__device__ __forceinline__ void gcore_glb(
    const unsigned short* __restrict__ wf,
    const unsigned short* p0, const unsigned short* p1,
    int mt, int c, int l4, int lane, ffrag* acc)
{
    const char* wp = (const char*)wf + (size_t)lane * 16;
#pragma unroll
    for (int s = 0; s < 16; ++s) {
        const int off = (((s * 4 + l4) ^ (c & 7)) << 3);
        bfrag bh = *(const bfrag*)(p0 + (size_t)c * 512 + off);
        bfrag bl = *(const bfrag*)(p1 + (size_t)c * 512 + off);
#pragma unroll
        for (int g = 0; g < G; ++g) {
            const char* ap = wp + (size_t)((g * 32 + mt) * 32 + s * 2) * 1024;
            bfrag ah = *(const bfrag*)ap;
            bfrag al = *(const bfrag*)(ap + 1024);
            acc[g] = __builtin_amdgcn_mfma_f32_16x16x32_bf16(ah, bh, acc[g], 0, 0, 0);
            acc[g] = __builtin_amdgcn_mfma_f32_16x16x32_bf16(ah, bl, acc[g], 0, 0, 0);
            acc[g] = __builtin_amdgcn_mfma_f32_16x16x32_bf16(al, bh, acc[g], 0, 0, 0);
        }
    }
}

// ---------- dots phase1 (wave 0 only; A from global wdot, B from LDS) -------
__device__ __forceinline__ void dots_p1(
    const unsigned short* BL, const unsigned short* __restrict__ wdotg,
    int c, int l4, int lane, float (*dls)[17])
{
    ffrag a = {0.f, 0.f, 0.f, 0.f};
    const char* wp = (const char*)wdotg + (size_t)lane * 16;
#pragma unroll
    for (int s = 0; s < 16; ++s) {
        const int off = (((s * 4 + l4) ^ (c & 7)) << 3);
        bfrag bh = *(const bfrag*)(BL + (size_t)c * 512 + off);
        bfrag bl = *(const bfrag*)(BL + 8192 + (size_t)c * 512 + off);
        bfrag ah = *(const bfrag*)(wp + (size_t)(s * 2) * 1024);
        bfrag al = *(const bfrag*)(wp + (size_t)(s * 2) * 1024 + 1024);
        a = __builtin_amdgcn_mfma_f32_16x16x32_bf16(ah, bh, a, 0, 0, 0);
        a = __builtin_amdgcn_mfma_f32_16x16x32_bf16(ah, bl, a, 0, 0, 0);
        a = __builtin_amdgcn_mfma_f32_16x16x32_bf16(al, bh, a, 0, 0, 0);
    }
#pragma unroll
    for (int r = 0; r < 4; ++r) dls[(l4 << 2) + r][c] = a[r];
}

// ---------- the pipelined persistent kernel ---------------------------------
// bid>>4: 0=gruLo 1=gruHi 2=postLo 3=postHi ; bid&15 = chain (2 col-groups)
__global__ __launch_bounds__(NTHR, 1) void k_pipe(
    const float* __restrict__ z, const float* __restrict__ dep,
    const float* __restrict__ xenc,
    const float* __restrict__ blin1, const float* __restrict__ bvert,
    const float* __restrict__ bedge, const float* __restrict__ bgate,
    const float* __restrict__ bmap,
    const float* __restrict__ Wih, const float* __restrict__ bih,
    const float* __restrict__ bhh,
    const unsigned short* __restrict__ wlin,
    const unsigned short* __restrict__ wpost,
    const unsigned short* __restrict__ whhf,
    const unsigned short* __restrict__ wdot,
    int* __restrict__ bars, unsigned short* __restrict__ rot,
    float* __restrict__ out)
{
    __shared__ unsigned short BL[16384];           // 32 KB B staging
    __shared__ float lWih[3 * HH * CC];            // gru: Wih ; post: [0..HH)=blin1
    __shared__ float lb1[3 * HH], lb2[3 * HH];     // gru: bih,bhh ; post: bgate,bmap
    __shared__ int   scls[SS][32];
    __shared__ float dls[16][17];
    __shared__ float sA[SS][32], sE[SS][32];

    const int bid = blockIdx.x, tid = threadIdx.x;
    const int lane = tid & 63, wv = tid >> 6;
    const int l4 = lane >> 4, c = lane & 15;
    const int role = bid >> 4, chain = bid & 15, half = role & 1;
    const int mt = half * 16 + wv;
    int* FH = bars;
    int* FI = bars + 1024;

    if (role < 2) {
        // =================== GRU block ===================
        bfrag wr[96];
#pragma unroll
        for (int i = 0; i < 96; ++i) {
            const int g = i >> 5, s = (i >> 1) & 15, p = i & 1;
            wr[i] = *(const bfrag*)((const char*)whhf
                     + (size_t)((g * 32 + mt) * 32 + s * 2 + p) * 1024 + lane * 16);
        }
        for (int i = tid; i < 3 * HH * CC; i += NTHR) lWih[i] = Wih[i];
        for (int i = tid; i < 3 * HH; i += NTHR) { lb1[i] = bih[i]; lb2[i] = bhh[i]; }
        if (tid < SS * 32) {
            int t = tid >> 5, lc = tid & 31;
            const float* xp = xenc + (((size_t)(chain * 32 + lc)) * SS + t) * CC;
            int cv = 0;
#pragma unroll
            for (int cc = 0; cc < CC; ++cc) if (xp[cc] > 0.5f) cv = cc;
            scls[t][lc] = cv;
        }
        __syncthreads();

        for (int t = 0; t < SS; ++t) {
#pragma unroll
            for (int gi = 0; gi < 2; ++gi) {
                const int g = chain * 2 + gi;
                waitpair(FI + ((g << 4) + t) * 2);
                stage_slot_lds(rot + (size_t)(g * 32 + t) * 16384, BL, tid);
                __syncthreads();
                ffrag acc[3];
#pragma unroll
                for (int i = 0; i < 3; ++i) acc[i] = ffrag{0.f, 0.f, 0.f, 0.f};
#pragma unroll
                for (int s = 0; s < 16; ++s) {
                    const int off = (((s * 4 + l4) ^ (c & 7)) << 3);
                    bfrag bh = *(const bfrag*)(BL + (size_t)c * 512 + off);
                    bfrag bl = *(const bfrag*)(BL + 8192 + (size_t)c * 512 + off);
#pragma unroll
                    for (int g3 = 0; g3 < 3; ++g3) {
                        acc[g3] = __builtin_amdgcn_mfma_f32_16x16x32_bf16(wr[g3*32+s*2],   bh, acc[g3], 0, 0, 0);
                        acc[g3] = __builtin_amdgcn_mfma_f32_16x16x32_bf16(wr[g3*32+s*2],   bl, acc[g3], 0, 0, 0);
                        acc[g3] = __builtin_amdgcn_mfma_f32_16x16x32_bf16(wr[g3*32+s*2+1], bh, acc[g3], 0, 0, 0);
                    }
                }
                float hp[4];
                readH(BL, BL + 8192, c, mt, l4, hp);
                const int rbase = mt * 16 + (l4 << 2);
                const int cc = scls[t][gi * 16 + c];
                float v[4];
#pragma unroll
                for (int r = 0; r < 4; ++r) {
                    int rr = rbase + r;
                    if (rr < HH) {
                        float rgt = sigm(lWih[rr * CC + cc] + lb1[rr] + acc[0][r] + lb2[rr]);
                        float ugt = sigm(lWih[(HH + rr) * CC + cc] + lb1[HH + rr] + acc[1][r] + lb2[HH + rr]);
                        float ngt = tanhf(lWih[(2 * HH + rr) * CC + cc] + lb1[2 * HH + rr]
                                          + rgt * (acc[2][r] + lb2[2 * HH + rr]));
                        v[r] = (1.f - ugt) * ngt + ugt * hp[r];
                    } else v[r] = 0.f;
                }
                store_slot(rot + (size_t)(g * 32 + 16 + t) * 16384, c, rbase, v);
                __syncthreads();
                if (tid == 0) setflag(FH + ((g << 4) + t) * 2 + half);
            }
        }
    } else {
        // =================== POST block ===================
        bfrag wr[64];
#pragma unroll
        for (int i = 0; i < 64; ++i) {
            const int g = i >> 5, s = (i >> 1) & 15, p = i & 1;
            wr[i] = *(const bfrag*)((const char*)wpost
                     + (size_t)((g * 32 + mt) * 32 + s * 2 + p) * 1024 + lane * 16);
        }
        for (int i = tid; i < HH; i += NTHR) { lb1[i] = bgate[i]; lb2[i] = bmap[i]; lWih[i] = blin1[i]; }
        if (role == 2) {   // zero this chain's 32-col dep-out slice
            for (int i = tid; i < 32 * 64; i += NTHR) {
                int col = i >> 6, q = i & 63;
                ((float4*)(out + (size_t)(chain * 32 + col) * (SS * SS)))[q] =
                    make_float4(0.f, 0.f, 0.f, 0.f);
            }
        }
        __syncthreads();

        // ---- g0 (+ dots(-1) on postLo, on the staged g0 OUTPUT) ----
        for (int gi = 0; gi < 2; ++gi) {
            const int g = chain * 2 + gi;
            {
                int col = tid >> 6, gr = tid & 63;
                const float* zp = z + (size_t)(chain * 32 + gi * 16 + col) * HH;
                unsigned h8[8], l8[8];
#pragma unroll
                for (int j = 0; j < 8; ++j) {
                    int k = gr * 8 + j;
                    float w = (k < HH) ? zp[k] : 0.f;
                    unsigned short hb = f2bf(w);
                    h8[j] = hb; l8[j] = f2bf(w - bf2f(hb));
                }
                uint4 uh, ul;
                uh.x = h8[0] | (h8[1] << 16); uh.y = h8[2] | (h8[3] << 16);
                uh.z = h8[4] | (h8[5] << 16); uh.w = h8[6] | (h8[7] << 16);
                ul.x = l8[0] | (l8[1] << 16); ul.y = l8[2] | (l8[3] << 16);
                ul.z = l8[4] | (l8[5] << 16); ul.w = l8[6] | (l8[7] << 16);
                const int off = (gr ^ (col & 7)) << 3;
                *(uint4*)(BL + col * 512 + off) = uh;
                *(uint4*)(BL + 8192 + col * 512 + off) = ul;
            }
            __syncthreads();
            ffrag a0 = {0.f, 0.f, 0.f, 0.f};
            gcore_glb<1>(wlin, BL, BL + 8192, mt, c, l4, lane, &a0);
            const int rbase = mt * 16 + (l4 << 2);
            float v[4];
#pragma unroll
            for (int r = 0; r < 4; ++r) {
                int rr = rbase + r;
                v[r] = (rr < HH) ? a0[r] + lWih[rr] : 0.f;
            }
            store_slot(rot + (size_t)(g * 32 + 0) * 16384, c, rbase, v);
            __syncthreads();
            if (tid == 0) setflag(FI + ((g << 4) + 0) * 2 + half);
            if (role == 2) {
                // FIX (r8 bug): dots(-1) must read the g0 OUTPUT, not z.
                // Wait for BOTH g0 halves, stage h_in(0) slot into BL, then dot.
                waitpair(FI + ((g << 4) + 0) * 2);
                stage_slot_lds(rot + (size_t)(g * 32 + 0) * 16384, BL, tid);
                __syncthreads();
                if (wv == 0) dots_p1(BL, wdot, c, l4, lane, dls);
                __syncthreads();
                if (tid < 16) {
                    const int b = g * 16 + tid;
                    float lv[CC], mx = -1e30f;
#pragma unroll
                    for (int q = 0; q < CC; ++q) { lv[q] = dls[2 + q][tid] + bvert[q]; mx = fmaxf(mx, lv[q]); }
                    float sum = 0.f, ev[CC];
#pragma unroll
                    for (int q = 0; q < CC; ++q) { ev[q] = expf(lv[q] - mx); sum += ev[q]; }
                    float inv = 1.f / sum;
#pragma unroll
                    for (int q = 0; q < CC; ++q)
                        out[OFF_ENC + ((size_t)b * SS + 0) * CC + q] = ev[q] * inv;
                }
            }
            __syncthreads();
        }

        // ---- timestep loop ----
        const int tmax = (role == 3) ? (SS - 1) : SS;
        for (int t = 0; t < tmax; ++t) {
            for (int gi = 0; gi < 2; ++gi) {
                const int g = chain * 2 + gi;
                waitpair(FH + ((g << 4) + t) * 2);
                stage_slot_lds(rot + (size_t)(g * 32 + 16 + t) * 16384, BL, tid);
                __syncthreads();
                if (t < SS - 1) {
                    ffrag acc[2];
                    acc[0] = ffrag{0.f, 0.f, 0.f, 0.f}; acc[1] = ffrag{0.f, 0.f, 0.f, 0.f};
#pragma unroll
                    for (int s = 0; s < 16; ++s) {
                        const int off = (((s * 4 + l4) ^ (c & 7)) << 3);
                        bfrag bh = *(const bfrag*)(BL + (size_t)c * 512 + off);
                        bfrag bl = *(const bfrag*)(BL + 8192 + (size_t)c * 512 + off);
#pragma unroll
                        for (int g2 = 0; g2 < 2; ++g2) {
                            acc[g2] = __builtin_amdgcn_mfma_f32_16x16x32_bf16(wr[g2*32+s*2],   bh, acc[g2], 0, 0, 0);
                            acc[g2] = __builtin_amdgcn_mfma_f32_16x16x32_bf16(wr[g2*32+s*2],   bl, acc[g2], 0, 0, 0);
                            acc[g2] = __builtin_amdgcn_mfma_f32_16x16x32_bf16(wr[g2*32+s*2+1], bh, acc[g2], 0, 0, 0);
                        }
                    }
                    const int rbase = mt * 16 + (l4 << 2);
                    const float d = dep[(size_t)(g * 16 + c) * (SS * SS) + (t + 1) * SS + t];
                    float v[4];
#pragma unroll
                    for (int r = 0; r < 4; ++r) {
                        int rr = rbase + r;
                        if (rr < HH) {
                            float bg = lb1[rr], bm = lb2[rr];
                            float cv = sigm(bg) * bm;
                            float f = sigm(acc[0][r] + bg) * (acc[1][r] + bm);
                            v[r] = (d != 0.f) ? (f + 15.f * cv) : (16.f * cv);
                        } else v[r] = 0.f;
                    }
                    store_slot(rot + (size_t)(g * 32 + t + 1) * 16384, c, rbase, v);
                }
                if (role == 2 && wv == 0) dots_p1(BL, wdot, c, l4, lane, dls);
                __syncthreads();
                if (t < SS - 1 && tid == 0) setflag(FI + ((g << 4) + t + 1) * 2 + half);
                if (role == 2 && tid < 16) {
                    const int b = g * 16 + tid;
                    float v9[9];
#pragma unroll
                    for (int j = 0; j < 9; ++j) v9[j] = dls[j][tid];
                    sA[t][gi * 16 + tid] = v9[0]; sE[t][gi * 16 + tid] = v9[1];
                    if (t <= SS - 2) {
                        float lv[CC], mx = -1e30f;
#pragma unroll
                        for (int q = 0; q < CC; ++q) { lv[q] = v9[2 + q] + bvert[q]; mx = fmaxf(mx, lv[q]); }
                        float sum = 0.f, ev[CC];
#pragma unroll
                        for (int q = 0; q < CC; ++q) { ev[q] = expf(lv[q] - mx); sum += ev[q]; }
                        float inv = 1.f / sum;
#pragma unroll
                        for (int q = 0; q < CC; ++q)
                            out[OFF_ENC + ((size_t)b * SS + (t + 1)) * CC + q] = ev[q] * inv;
                    }
                    if (t >= 1) {
                        float be = bedge[0];
                        out[(size_t)b * SS * SS + t * SS + (t - 1)] =
                            (sA[t - 1][gi * 16 + tid] + sE[t - 1][gi * 16 + tid] + be >= 0.f) ? 1.f : 0.f;
                        for (int vj = 0; vj <= t - 2; ++vj)
                            out[(size_t)b * SS * SS + t * SS + vj] =
                                (v9[0] + sE[vj][gi * 16 + tid] + be >= 0.f) ? 1.f : 0.f;
                    }
                }
            }
        }
    }
}

extern "C" void kernel_launch(void* const* d_in, const int* in_sizes, int n_in,
                              void* d_out, int out_size, void* d_ws, size_t ws_size,
                              hipStream_t stream)
{
    const float* z     = (const float*)d_in[0];
    const float* dep   = (const float*)d_in[1];
    const float* xenc  = (const float*)d_in[2];
    const float* Wlin1 = (const float*)d_in[3];
    const float* blin1 = (const float*)d_in[4];
    const float* Wvert = (const float*)d_in[5];
    const float* bvert = (const float*)d_in[6];
    const float* Wedge = (const float*)d_in[7];
    const float* bedge = (const float*)d_in[8];
    const float* Wgate = (const float*)d_in[9];
    const float* bgate = (const float*)d_in[10];
    const float* Wmap  = (const float*)d_in[11];
    const float* bmap  = (const float*)d_in[12];
    const float* Wih   = (const float*)d_in[13];
    const float* bih   = (const float*)d_in[14];
    const float* Whh   = (const float*)d_in[15];
    const float* bhh   = (const float*)d_in[16];
    float* out = (float*)d_out;
    float* ws  = (float*)d_ws;

    unsigned short* wlin  = (unsigned short*)(ws + O_WLIN);
    unsigned short* wpost = (unsigned short*)(ws + O_WPOST);
    unsigned short* whhf  = (unsigned short*)(ws + O_WHH);
    unsigned short* wdot  = (unsigned short*)(ws + O_WDOT);
    int* bars             = (int*)(ws + O_FLAGS);
    unsigned short* rot   = (unsigned short*)(ws + O_ROT);

    k_wprep<<<772, 256, 0, stream>>>(Wlin1, Wgate, Wmap, Whh, Wedge, Wvert,
                                     wlin, wpost, whhf, wdot);
    k_finit<<<8, 256, 0, stream>>>(bars);
    k_pipe<<<NBLK, NTHR, 0, stream>>>(z, dep, xenc, blin1, bvert, bedge,
                                      bgate, bmap, Wih, bih, bhh,
                                      wlin, wpost, whhf, wdot, bars, rot, out);
}